// Round 2
// baseline (161.442 us; speedup 1.0000x reference)
//
#include <hip/hip_runtime.h>

// LengthRegulator: out[b, t, :] = x[b, j, :] where j = searchsorted(cumsum(dur[b]), t, 'right'),
// zero for t >= total duration. B=16, L=512, D=512, T_MAX=4096. fp32 in/out.
//
// R7 (resubmit; round-1 bench never ran — GPU acquisition timeout):
//  - ROWS 8 -> 16 (grid 8192 -> 4096 blocks): halves redundant cumsum/search work.
//  - Token indices for all 8 rows/thread are precomputed in one monotone LDS walk,
//    THEN all 8 gather loads issue as independent VMEM ops (was: 1 dependent load
//    behind a serial LDS walk per iteration -> ~1 load in flight per thread).
//  - Blocks entirely past `total` (~50% of all blocks, E[total]=1792 of 4096) take a
//    pure nontemporal zero-fill path: no search, no gather, memset-rate streaming.
//  - Nontemporal 16B stores kept: output is 134 MB write-once, keep it out of L2.

#define BATCH 16
#define LTOK  512
#define DIM   512
#define TMAX  4096
#define ROWS  16          // output rows per block
#define RPT   (ROWS / 2)  // rows per thread (256 thr: 128 lanes x 2 row-halves)

typedef float nt_f4 __attribute__((ext_vector_type(4)));  // 16B, same layout as float4

__global__ __launch_bounds__(256) void MRTE_fused_kernel(const float* __restrict__ x,
                                                         const int* __restrict__ dur,
                                                         float* __restrict__ out) {
    __shared__ int se[LTOK];
    const int b    = blockIdx.y;
    const int t0   = blockIdx.x * ROWS;
    const int tid  = threadIdx.x;
    const int half = tid >> 7;    // 0 or 1: which row of the pair
    const int lane = tid & 127;   // 16B column (128 * 16B = 2KB row)

    // ---- wave 0: inclusive cumsum of dur[b][0..511] into se[] ----
    if (tid < 64) {
        const int4* __restrict__ d4 = reinterpret_cast<const int4*>(dur + b * LTOK);
        int4 a = d4[tid * 2];
        int4 c = d4[tid * 2 + 1];
        int p0 = a.x;
        int p1 = p0 + a.y;
        int p2 = p1 + a.z;
        int p3 = p2 + a.w;
        int p4 = p3 + c.x;
        int p5 = p4 + c.y;
        int p6 = p5 + c.z;
        int p7 = p6 + c.w;
        int s = p7;
        #pragma unroll
        for (int off = 1; off < 64; off <<= 1) {   // 64-lane inclusive shfl scan
            int n = __shfl_up(s, off, 64);
            if (tid >= off) s += n;
        }
        const int base = s - p7;                    // exclusive prefix of this lane's chunk
        int4* o = reinterpret_cast<int4*>(se + tid * 8);
        o[0] = make_int4(base + p0, base + p1, base + p2, base + p3);
        o[1] = make_int4(base + p4, base + p5, base + p6, base + p7);
    }
    __syncthreads();

    const int total = se[LTOK - 1];

    nt_f4* __restrict__ ob =
        reinterpret_cast<nt_f4*>(out + ((size_t)b * TMAX + (size_t)t0) * DIM);

    // ---- fast path: block entirely in the zero tail -> streaming zero-fill ----
    if (t0 >= total) {
        #pragma unroll
        for (int i = 0; i < RPT; ++i)
            __builtin_nontemporal_store((nt_f4)0.f,
                                        &ob[(size_t)(2 * i + half) * (DIM / 4) + lane]);
        return;
    }

    // ---- block-uniform binary search: first j with se[j] > t0 (LDS broadcast) ----
    int lo = 0, hi = LTOK;
    while (lo < hi) {
        int mid = (lo + hi) >> 1;
        if (se[mid] > t0) hi = mid; else lo = mid + 1;
    }

    const nt_f4* __restrict__ xb =
        reinterpret_cast<const nt_f4*>(x + (size_t)b * LTOK * DIM);

    // ---- phase 1: resolve all token indices (monotone cursor, LDS-hit walk) ----
    int jr[RPT];
    int jt = lo;
    #pragma unroll
    for (int i = 0; i < RPT; ++i) {
        const int t = t0 + 2 * i + half;
        if (t < total) {
            while (se[jt] <= t) ++jt;   // avg ~0.6 steps per row at E[dur]=3.5
            jr[i] = jt;
        } else {
            jr[i] = -1;
        }
    }

    // ---- phase 2: independent gather loads + streaming stores ----
    #pragma unroll
    for (int i = 0; i < RPT; ++i) {
        nt_f4 v = (nt_f4)0.f;
        if (jr[i] >= 0) v = xb[(size_t)jr[i] * (DIM / 4) + lane];
        __builtin_nontemporal_store(v, &ob[(size_t)(2 * i + half) * (DIM / 4) + lane]);
    }
}

extern "C" void kernel_launch(void* const* d_in, const int* in_sizes, int n_in,
                              void* d_out, int out_size, void* d_ws, size_t ws_size,
                              hipStream_t stream) {
    const float* x   = (const float*)d_in[0];        // [B, L, D] fp32
    const int*   dur = (const int*)d_in[1];          // [B, L] int32
    // d_in[2] = mel_max_length scalar (static 4096; hard-coded)
    float* out = (float*)d_out;                       // [B, TMAX, D] fp32

    MRTE_fused_kernel<<<dim3(TMAX / ROWS, BATCH), 256, 0, stream>>>(x, dur, out);
}

// Round 3
// 157.701 us; speedup vs baseline: 1.0237x; 1.0237x over previous
//
#include <hip/hip_runtime.h>

// LengthRegulator: out[b, t, :] = x[b, j, :] where j = searchsorted(cumsum(dur[b]), t, 'right'),
// zero for t >= total duration. B=16, L=512, D=512, T_MAX=4096. fp32 in/out.
//
// R8: kill the per-block serial LDS-latency prologue.
//  R7 post-mortem: phase-splitting the gather loads was NEUTRAL (156->161 us ~ noise),
//  so load ILP was not the limiter. Remaining per-block serial chain: block-uniform
//  binary search (9 dependent LDS reads) + per-thread cursor walk (~8-13 dependent LDS
//  reads) ~= 2.5k cycles of latency with all 4 waves stalled, vs ~3.1k cycles of useful
//  store drain per block -> ~45% duty-cycle tax.
//  Change: wave 0 already holds all 512 cumsum ends in registers after the shfl scan.
//  searchsorted(ends, t, 'right') == #{ends <= t}, so compute the token index for all
//  16 block rows directly: 8 compares/lane/row + packed 16-bit butterfly reduction
//  (pure VALU, ~0.8k cyc, no LDS chain). se[512] LDS array deleted (2 KB -> 68 B);
//  gather path reads stok[r] (LDS broadcast) then issues 8 independent loads + stores.
//  Nontemporal stores unchanged (next A/B if this is neutral).

#define BATCH 16
#define LTOK  512
#define DIM   512
#define TMAX  4096
#define ROWS  16          // output rows per block; 256 thr = 2 row-halves x 128 lanes

typedef float nt_f4 __attribute__((ext_vector_type(4)));  // 16B, same layout as float4

__global__ __launch_bounds__(256) void MRTE_fused_kernel(const float* __restrict__ x,
                                                         const int* __restrict__ dur,
                                                         float* __restrict__ out) {
    __shared__ int stok[ROWS];   // token index per block row
    __shared__ int stotal;       // total frames for this batch
    const int b    = blockIdx.y;
    const int t0   = blockIdx.x * ROWS;
    const int tid  = threadIdx.x;
    const int half = tid >> 7;   // 0/1: rows 0-7 vs 8-15
    const int lane = tid & 127;  // 16B column (128 * 16B = 2KB row)

    // ---- wave 0: scan of dur[b][0..511] entirely in registers + direct tok compute ----
    if (tid < 64) {
        const int4* __restrict__ d4 = reinterpret_cast<const int4*>(dur + b * LTOK);
        int4 a = d4[tid * 2];
        int4 c = d4[tid * 2 + 1];
        int p0 = a.x;
        int p1 = p0 + a.y;
        int p2 = p1 + a.z;
        int p3 = p2 + a.w;
        int p4 = p3 + c.x;
        int p5 = p4 + c.y;
        int p6 = p5 + c.z;
        int p7 = p6 + c.w;
        int s = p7;
        #pragma unroll
        for (int off = 1; off < 64; off <<= 1) {   // 64-lane inclusive shfl scan
            int n = __shfl_up(s, off, 64);
            if (tid >= off) s += n;
        }
        const int base = s - p7;                    // exclusive prefix of this lane's chunk
        // lane holds cumsum ends for tokens 8*tid .. 8*tid+7:
        const int e0 = base + p0, e1 = base + p1, e2 = base + p2, e3 = base + p3;
        const int e4 = base + p4, e5 = base + p5, e6 = base + p6, e7 = base + p7;
        const int tot = __shfl(s, 63, 64);
        if (tid == 63) stotal = s;

        if (t0 < tot) {
            // j(t) = #{ends <= t} summed over all 512 ends.
            // Pack two row-counts per 32-bit reg (sums <= 512, no field overflow).
            unsigned pk[8];
            #pragma unroll
            for (int rp = 0; rp < 8; ++rp) {
                const int ta = t0 + 2 * rp;
                const int tb = ta + 1;
                unsigned ca = (unsigned)((e0 <= ta) + (e1 <= ta) + (e2 <= ta) + (e3 <= ta) +
                                         (e4 <= ta) + (e5 <= ta) + (e6 <= ta) + (e7 <= ta));
                unsigned cb = (unsigned)((e0 <= tb) + (e1 <= tb) + (e2 <= tb) + (e3 <= tb) +
                                         (e4 <= tb) + (e5 <= tb) + (e6 <= tb) + (e7 <= tb));
                unsigned p = ca | (cb << 16);
                #pragma unroll
                for (int off = 32; off >= 1; off >>= 1)
                    p += (unsigned)__shfl_xor((int)p, off, 64);
                pk[rp] = p;
            }
            if (tid == 0) {
                #pragma unroll
                for (int rp = 0; rp < 8; ++rp) {
                    stok[2 * rp]     = (int)(pk[rp] & 0xffffu);
                    stok[2 * rp + 1] = (int)(pk[rp] >> 16);
                }
            }
        }
    }
    __syncthreads();

    const int total = stotal;
    nt_f4* __restrict__ ob =
        reinterpret_cast<nt_f4*>(out + ((size_t)b * TMAX + (size_t)t0) * DIM);

    // ---- fast path: block entirely in the zero tail -> streaming zero-fill ----
    if (t0 >= total) {
        #pragma unroll
        for (int i = 0; i < 8; ++i)
            __builtin_nontemporal_store((nt_f4)0.f,
                                        &ob[(size_t)(half * 8 + i) * (DIM / 4) + lane]);
        return;
    }

    const nt_f4* __restrict__ xb =
        reinterpret_cast<const nt_f4*>(x + (size_t)b * LTOK * DIM);
    const int tbase = t0 + half * 8;

    // phase 1: all 8 token indices (LDS broadcast reads, independent)
    int j[8];
    #pragma unroll
    for (int i = 0; i < 8; ++i)
        j[i] = (tbase + i < total) ? stok[half * 8 + i] : -1;

    // phase 2: independent gather loads + streaming stores
    #pragma unroll
    for (int i = 0; i < 8; ++i) {
        nt_f4 v = (nt_f4)0.f;
        if (j[i] >= 0) v = xb[(size_t)j[i] * (DIM / 4) + lane];
        __builtin_nontemporal_store(v, &ob[(size_t)(half * 8 + i) * (DIM / 4) + lane]);
    }
}

extern "C" void kernel_launch(void* const* d_in, const int* in_sizes, int n_in,
                              void* d_out, int out_size, void* d_ws, size_t ws_size,
                              hipStream_t stream) {
    const float* x   = (const float*)d_in[0];        // [B, L, D] fp32
    const int*   dur = (const int*)d_in[1];          // [B, L] int32
    // d_in[2] = mel_max_length scalar (static 4096; hard-coded)
    float* out = (float*)d_out;                       // [B, TMAX, D] fp32

    MRTE_fused_kernel<<<dim3(TMAX / ROWS, BATCH), 256, 0, stream>>>(x, dur, out);
}

// Round 4
// 154.496 us; speedup vs baseline: 1.0450x; 1.0207x over previous
//
#include <hip/hip_runtime.h>

// LengthRegulator: out[b, t, :] = x[b, j, :] where j = searchsorted(cumsum(dur[b]), t, 'right'),
// zero for t >= total duration. B=16, L=512, D=512, T_MAX=4096. fp32 in/out.
//
// R9: single-variable A/B — nontemporal stores -> plain cached stores.
//  R7 (load ILP) and R8 (prologue elimination) were both NEUTRAL => kernel is not
//  latency- or prologue-bound. Model: kernel ~30-34 us vs ~24 us BW floor
//  (134 MB write + ~17 MB read @ 6.3 TB/s); timed total is dominated by the
//  ~85 us harness poison fill + ~40 us fixed small-dispatch overhead.
//  The poison fill hits 6.4 TB/s with PLAIN stores; we use nt stores — the last
//  qualitative difference. If this A/B is neutral, the kernel is at its BW
//  ceiling and the session is done (ROOFLINE).

#define BATCH 16
#define LTOK  512
#define DIM   512
#define TMAX  4096
#define ROWS  16          // output rows per block; 256 thr = 2 row-halves x 128 lanes

typedef float f4v __attribute__((ext_vector_type(4)));  // 16B, same layout as float4

__global__ __launch_bounds__(256) void MRTE_fused_kernel(const float* __restrict__ x,
                                                         const int* __restrict__ dur,
                                                         float* __restrict__ out) {
    __shared__ int stok[ROWS];   // token index per block row
    __shared__ int stotal;       // total frames for this batch
    const int b    = blockIdx.y;
    const int t0   = blockIdx.x * ROWS;
    const int tid  = threadIdx.x;
    const int half = tid >> 7;   // 0/1: rows 0-7 vs 8-15
    const int lane = tid & 127;  // 16B column (128 * 16B = 2KB row)

    // ---- wave 0: scan of dur[b][0..511] entirely in registers + direct tok compute ----
    if (tid < 64) {
        const int4* __restrict__ d4 = reinterpret_cast<const int4*>(dur + b * LTOK);
        int4 a = d4[tid * 2];
        int4 c = d4[tid * 2 + 1];
        int p0 = a.x;
        int p1 = p0 + a.y;
        int p2 = p1 + a.z;
        int p3 = p2 + a.w;
        int p4 = p3 + c.x;
        int p5 = p4 + c.y;
        int p6 = p5 + c.z;
        int p7 = p6 + c.w;
        int s = p7;
        #pragma unroll
        for (int off = 1; off < 64; off <<= 1) {   // 64-lane inclusive shfl scan
            int n = __shfl_up(s, off, 64);
            if (tid >= off) s += n;
        }
        const int base = s - p7;                    // exclusive prefix of this lane's chunk
        // lane holds cumsum ends for tokens 8*tid .. 8*tid+7:
        const int e0 = base + p0, e1 = base + p1, e2 = base + p2, e3 = base + p3;
        const int e4 = base + p4, e5 = base + p5, e6 = base + p6, e7 = base + p7;
        const int tot = __shfl(s, 63, 64);
        if (tid == 63) stotal = s;

        if (t0 < tot) {
            // j(t) = #{ends <= t} summed over all 512 ends.
            // Pack two row-counts per 32-bit reg (sums <= 512, no field overflow).
            unsigned pk[8];
            #pragma unroll
            for (int rp = 0; rp < 8; ++rp) {
                const int ta = t0 + 2 * rp;
                const int tb = ta + 1;
                unsigned ca = (unsigned)((e0 <= ta) + (e1 <= ta) + (e2 <= ta) + (e3 <= ta) +
                                         (e4 <= ta) + (e5 <= ta) + (e6 <= ta) + (e7 <= ta));
                unsigned cb = (unsigned)((e0 <= tb) + (e1 <= tb) + (e2 <= tb) + (e3 <= tb) +
                                         (e4 <= tb) + (e5 <= tb) + (e6 <= tb) + (e7 <= tb));
                unsigned p = ca | (cb << 16);
                #pragma unroll
                for (int off = 32; off >= 1; off >>= 1)
                    p += (unsigned)__shfl_xor((int)p, off, 64);
                pk[rp] = p;
            }
            if (tid == 0) {
                #pragma unroll
                for (int rp = 0; rp < 8; ++rp) {
                    stok[2 * rp]     = (int)(pk[rp] & 0xffffu);
                    stok[2 * rp + 1] = (int)(pk[rp] >> 16);
                }
            }
        }
    }
    __syncthreads();

    const int total = stotal;
    f4v* __restrict__ ob =
        reinterpret_cast<f4v*>(out + ((size_t)b * TMAX + (size_t)t0) * DIM);

    // ---- fast path: block entirely in the zero tail -> plain streaming zero-fill ----
    if (t0 >= total) {
        #pragma unroll
        for (int i = 0; i < 8; ++i)
            ob[(size_t)(half * 8 + i) * (DIM / 4) + lane] = (f4v)0.f;
        return;
    }

    const f4v* __restrict__ xb =
        reinterpret_cast<const f4v*>(x + (size_t)b * LTOK * DIM);
    const int tbase = t0 + half * 8;

    // phase 1: all 8 token indices (LDS broadcast reads, independent)
    int j[8];
    #pragma unroll
    for (int i = 0; i < 8; ++i)
        j[i] = (tbase + i < total) ? stok[half * 8 + i] : -1;

    // phase 2: independent gather loads + plain stores
    #pragma unroll
    for (int i = 0; i < 8; ++i) {
        f4v v = (f4v)0.f;
        if (j[i] >= 0) v = xb[(size_t)j[i] * (DIM / 4) + lane];
        ob[(size_t)(half * 8 + i) * (DIM / 4) + lane] = v;
    }
}

extern "C" void kernel_launch(void* const* d_in, const int* in_sizes, int n_in,
                              void* d_out, int out_size, void* d_ws, size_t ws_size,
                              hipStream_t stream) {
    const float* x   = (const float*)d_in[0];        // [B, L, D] fp32
    const int*   dur = (const int*)d_in[1];          // [B, L] int32
    // d_in[2] = mel_max_length scalar (static 4096; hard-coded)
    float* out = (float*)d_out;                       // [B, TMAX, D] fp32

    MRTE_fused_kernel<<<dim3(TMAX / ROWS, BATCH), 256, 0, stream>>>(x, dur, out);
}